// Round 16
// baseline (90.143 us; speedup 1.0000x reference)
//
#include <hip/hip_runtime.h>
#include <hip/hip_cooperative_groups.h>

namespace cg = cooperative_groups;

// ForegroundConsistencyLoss - N=8192, C=20.
// loss = mean over pairs {both fg, d2>4} of relu(cos_sim(logits_i, logits_j)).
//
// v7: ONE cooperative kernel. 528 blocks, each grid-strides over <=2 of the
// 1056 upper-triangle 128x256 super-tiles (4 rowgroups x 8 colgroups), preps
// its own points into LDS fragments (r8-verified layout), MFMA + triangle
// weighting (skip cg<rg, x2 cg>rg, x1 diag - verified r8-r14), per-block
// register partials -> one uncontended slot -> grid.sync -> block 0 reduces.
// No contended atomics (v3 lesson), no inter-kernel gaps (v6 lesson: the
// 2-dispatch structure cost ~10us of 18.9).

#define C_CLS 20

typedef __attribute__((ext_vector_type(8)))  short bh8;    // 8 bf16 (4 VGPRs)
typedef __attribute__((ext_vector_type(16))) float fx16;   // 16 f32 acc
typedef __attribute__((ext_vector_type(4)))  float f4;

static __device__ __forceinline__ short f2bf(float x) {
    unsigned u = __float_as_uint(x);
    unsigned r = (u + 0x7fffu + ((u >> 16) & 1u)) >> 16;
    return (short)r;
}

struct Rec { bh8 v0, v1, v2, d; };

// bside=false -> d = A'-row [-2x,-2y,-2z,sq',1]; bside=true -> d = B'-col
// [x,y,z,1,sq'].  sq' = fg ? |p|^2 : -1e30 (folds fg mask into d2>4 test).
static __device__ __forceinline__ Rec make_rec(const float* __restrict__ pc,
                                               const float* __restrict__ logits,
                                               int i, bool bside) {
    const f4* lg4 = (const f4*)(logits + (size_t)i * C_CLS);  // 80B stride
    float l[C_CLS];
#pragma unroll
    for (int q = 0; q < 5; ++q) {
        f4 v = lg4[q];
        l[q * 4 + 0] = v.x; l[q * 4 + 1] = v.y; l[q * 4 + 2] = v.z; l[q * 4 + 3] = v.w;
    }
    float m = l[1];
#pragma unroll
    for (int k = 2; k < C_CLS; ++k) m = fmaxf(m, l[k]);
    bool fg = m > l[0];                 // argmax != 0 (ties -> idx 0 -> bg)
    float ss = 0.f;
#pragma unroll
    for (int k = 0; k < C_CLS; ++k) ss = fmaf(l[k], l[k], ss);
    float inv = 1.0f / fmaxf(sqrtf(ss), 1e-8f);
    float px = pc[i * 3 + 0], py = pc[i * 3 + 1], pz = pc[i * 3 + 2];
    float sq = px * px + py * py + pz * pz;
    float sqp = fg ? sq : -1.0e30f;

    Rec rec;
    bh8 vz = {0, 0, 0, 0, 0, 0, 0, 0};
#pragma unroll
    for (int e = 0; e < 8; ++e) rec.v0[e] = f2bf(l[e] * inv);
#pragma unroll
    for (int e = 0; e < 8; ++e) rec.v1[e] = f2bf(l[8 + e] * inv);
    rec.v2 = vz;
#pragma unroll
    for (int e = 0; e < 4; ++e) rec.v2[e] = f2bf(l[16 + e] * inv);
    bh8 d = vz;
    if (!bside) {
        d[0] = f2bf(-2.0f * px); d[1] = f2bf(-2.0f * py); d[2] = f2bf(-2.0f * pz);
        d[3] = f2bf(sqp);        d[4] = f2bf(1.0f);
    } else {
        d[0] = f2bf(px); d[1] = f2bf(py); d[2] = f2bf(pz);
        d[3] = f2bf(1.0f); d[4] = f2bf(sqp);
    }
    rec.d = d;
    return rec;
}

// Super-tile st -> (R,C): row R covers col-blocks C in [R/2, gx), so row R
// has (gx - R/2) tiles; prefix P(R) = gx*R - floor((R-1)^2/4), P(0)=0.
__global__ void __launch_bounds__(256, 4)
fcl_coop(const float* __restrict__ pc, const float* __restrict__ logits,
         float* __restrict__ psums, int* __restrict__ pcnts,
         float* __restrict__ out, int NG, int nst) {
    const int tid = threadIdx.x;
    const int lane = tid & 63;
    const int w = tid >> 6;
    const int gx = NG >> 3, Rn = NG >> 2;

    __shared__ bh8 shAS[4 * 2 * 64];     // 8 KB
    __shared__ bh8 shAD[4 * 64];         // 4 KB
    __shared__ bh8 shBS[8 * 2 * 64];     // 16 KB
    __shared__ bh8 shBD[8 * 64];         // 8 KB
    const bh8 vz = {0, 0, 0, 0, 0, 0, 0, 0};

    float psD = 0.f, psO = 0.f;
    int   cnD = 0,   cnO = 0;

    for (int st = blockIdx.x; st < nst; st += gridDim.x) {
        // map st -> (R, C) via binary search on P(R)
        int lo = 0, hi = Rn - 1;
        while (lo < hi) {
            int mid = (lo + hi + 1) >> 1;
            int p = gx * mid - ((mid - 1) * (mid - 1)) / 4;
            if (p <= st) lo = mid; else hi = mid - 1;
        }
        const int R = lo;
        const int P = (R > 0) ? (gx * R - ((R - 1) * (R - 1)) / 4) : 0;
        const int C = (R >> 1) + (st - P);

        __syncthreads();                  // protect LDS reuse across iterations

        // prep B region: 256 points at C*256
        {
            Rec rec = make_rec(pc, logits, C * 256 + tid, true);
            int g = tid >> 5, r = tid & 31;
            shBS[(g * 2 + 0) * 64 + r]      = rec.v0;
            shBS[(g * 2 + 0) * 64 + r + 32] = rec.v1;
            shBS[(g * 2 + 1) * 64 + r]      = rec.v2;
            shBS[(g * 2 + 1) * 64 + r + 32] = vz;
            shBD[g * 64 + r]                = rec.d;
            shBD[g * 64 + r + 32]           = vz;
        }
        // prep A region: 128 points at R*128
        if (tid < 128) {
            Rec rec = make_rec(pc, logits, R * 128 + tid, false);
            int g = tid >> 5, r = tid & 31;
            shAS[(g * 2 + 0) * 64 + r]      = rec.v0;
            shAS[(g * 2 + 0) * 64 + r + 32] = rec.v1;
            shAS[(g * 2 + 1) * 64 + r]      = rec.v2;
            shAS[(g * 2 + 1) * 64 + r + 32] = vz;
            shAD[g * 64 + r]                = rec.d;
            shAD[g * 64 + r + 32]           = vz;
        }
        __syncthreads();

        const int rg = R * 4 + w;         // this wave's global row-group
        const bh8 aS0 = shAS[(w * 2 + 0) * 64 + lane];
        const bh8 aS1 = shAS[(w * 2 + 1) * 64 + lane];
        const bh8 aD  = shAD[w * 64 + lane];

#pragma unroll
        for (int k = 0; k < 8; ++k) {
            const int cg = C * 8 + k;     // wave-uniform
            if (cg < rg) continue;        // below diagonal
            bh8 b0 = shBS[(k * 2 + 0) * 64 + lane];
            bh8 b1 = shBS[(k * 2 + 1) * 64 + lane];
            bh8 bd = shBD[k * 64 + lane];
            fx16 accS = {0.f};
            accS = __builtin_amdgcn_mfma_f32_32x32x16_bf16(aS0, b0, accS, 0, 0, 0);
            accS = __builtin_amdgcn_mfma_f32_32x32x16_bf16(aS1, b1, accS, 0, 0, 0);
            fx16 accD = {0.f};
            accD = __builtin_amdgcn_mfma_f32_32x32x16_bf16(aD, bd, accD, 0, 0, 0);
            if (cg == rg) {
#pragma unroll
                for (int r2 = 0; r2 < 16; ++r2) {
                    bool cc = accD[r2] > 4.0f;
                    psD += cc ? fmaxf(accS[r2], 0.f) : 0.f;
                    cnD += cc ? 1 : 0;
                }
            } else {
#pragma unroll
                for (int r2 = 0; r2 < 16; ++r2) {
                    bool cc = accD[r2] > 4.0f;
                    psO += cc ? fmaxf(accS[r2], 0.f) : 0.f;
                    cnO += cc ? 1 : 0;
                }
            }
        }
    }

    // fold x2 off-diagonal weight; wave + block reduce into one slot
    float ps = psD + 2.0f * psO;
    int   cn = cnD + 2 * cnO;
#pragma unroll
    for (int off = 32; off > 0; off >>= 1) {
        ps += __shfl_down(ps, off);
        cn += __shfl_down(cn, off);
    }
    __shared__ float sps[4];
    __shared__ int   scs[4];
    if (lane == 0) { sps[w] = ps; scs[w] = cn; }
    __syncthreads();
    if (tid == 0) {
        psums[blockIdx.x] = sps[0] + sps[1] + sps[2] + sps[3];
        pcnts[blockIdx.x] = scs[0] + scs[1] + scs[2] + scs[3];
    }
    __threadfence();

    cg::this_grid().sync();

    if (blockIdx.x == 0) {
        float s = 0.f;
        int c = 0;
        for (int k = tid; k < (int)gridDim.x; k += 256) { s += psums[k]; c += pcnts[k]; }
#pragma unroll
        for (int off = 32; off > 0; off >>= 1) {
            s += __shfl_down(s, off);
            c += __shfl_down(c, off);
        }
        __shared__ float fps[4];
        __shared__ int   fcs[4];
        if (lane == 0) { fps[w] = s; fcs[w] = c; }
        __syncthreads();
        if (tid == 0) {
            float ts = fps[0] + fps[1] + fps[2] + fps[3];
            int   tc = fcs[0] + fcs[1] + fcs[2] + fcs[3];
            out[0] = (tc > 0) ? ts / (float)tc : 1.0f;
        }
    }
}

extern "C" void kernel_launch(void* const* d_in, const int* in_sizes, int n_in,
                              void* d_out, int out_size, void* d_ws, size_t ws_size,
                              hipStream_t stream) {
    const float* pc     = (const float*)d_in[0];  // [N,3]
    const float* logits = (const float*)d_in[1];  // [N,20]
    float* out = (float*)d_out;

    const int N  = in_sizes[0] / 3;               // 8192
    int NG = N / 32;                              // 256 groups
    const int gx = NG / 8, Rn = NG / 4;           // 32, 64
    const int nst = gx * Rn - ((Rn - 1) * (Rn - 1)) / 4;   // 1056 active tiles
    int nb = (nst + 1) / 2;                       // 528 blocks (<=2 tiles each)

    float* psums = (float*)d_ws;
    int*   pcnts = (int*)(psums + nb);

    void* args[] = {(void*)&pc, (void*)&logits, (void*)&psums, (void*)&pcnts,
                    (void*)&out, (void*)&NG, (void*)&nst};
    hipLaunchCooperativeKernel((void*)fcl_coop, dim3(nb), dim3(256), args, 0, stream);
}

// Round 18
// 40.631 us; speedup vs baseline: 2.2186x; 2.2186x over previous
//
#include <hip/hip_runtime.h>

// ForegroundConsistencyLoss - N=8192, C=20.
// loss = mean over pairs {both fg, d2>4} of relu(cos_sim(logits_i, logits_j)).
//
// v9 = v8 + deterministic ticket: hipMemsetAsync(ticket,0) each call, last
// TRUE arriver (old == nst-1) finalizes. v8 tripwire post-mortem: modulo
// ticket decoupled residue from arrival order under 0xAA poison -> the
// "last" block fired at arrival 790/1056 and read unwritten slots. First
// call's absmax 0.0 proved the fused math + cross-XCD fence visibility are
// correct; only the start-state assumption was wrong.
//
// Structure: 1056 blocks = 1056 upper-triangle 128x256 super-tiles (4 row-
// groups x 8 colgroups), one per block. Block preps its 384 points into LDS
// fragments (r8-verified layout), MFMA + triangle weighting (skip cg<rg,
// x2 cg>rg, x1 diag - verified r8-r16), private partial slot, one staggered
// ticket RMW (no contended bursts - v3 lesson; no grid.sync - v7 lesson).

#define C_CLS 20

typedef __attribute__((ext_vector_type(8)))  short bh8;    // 8 bf16 (4 VGPRs)
typedef __attribute__((ext_vector_type(16))) float fx16;   // 16 f32 acc
typedef __attribute__((ext_vector_type(4)))  float f4;

static __device__ __forceinline__ short f2bf(float x) {
    unsigned u = __float_as_uint(x);
    unsigned r = (u + 0x7fffu + ((u >> 16) & 1u)) >> 16;
    return (short)r;
}

struct Rec { bh8 v0, v1, v2, d; };

// bside=false -> d = A'-row [-2x,-2y,-2z,sq',1]; bside=true -> d = B'-col
// [x,y,z,1,sq'].  sq' = fg ? |p|^2 : -1e30 (folds fg mask into d2>4 test).
static __device__ __forceinline__ Rec make_rec(const float* __restrict__ pc,
                                               const float* __restrict__ logits,
                                               int i, bool bside) {
    const f4* lg4 = (const f4*)(logits + (size_t)i * C_CLS);  // 80B stride
    float l[C_CLS];
#pragma unroll
    for (int q = 0; q < 5; ++q) {
        f4 v = lg4[q];
        l[q * 4 + 0] = v.x; l[q * 4 + 1] = v.y; l[q * 4 + 2] = v.z; l[q * 4 + 3] = v.w;
    }
    float m = l[1];
#pragma unroll
    for (int k = 2; k < C_CLS; ++k) m = fmaxf(m, l[k]);
    bool fg = m > l[0];                 // argmax != 0 (ties -> idx 0 -> bg)
    float ss = 0.f;
#pragma unroll
    for (int k = 0; k < C_CLS; ++k) ss = fmaf(l[k], l[k], ss);
    float inv = 1.0f / fmaxf(sqrtf(ss), 1e-8f);
    float px = pc[i * 3 + 0], py = pc[i * 3 + 1], pz = pc[i * 3 + 2];
    float sq = px * px + py * py + pz * pz;
    float sqp = fg ? sq : -1.0e30f;

    Rec rec;
    bh8 vz = {0, 0, 0, 0, 0, 0, 0, 0};
#pragma unroll
    for (int e = 0; e < 8; ++e) rec.v0[e] = f2bf(l[e] * inv);
#pragma unroll
    for (int e = 0; e < 8; ++e) rec.v1[e] = f2bf(l[8 + e] * inv);
    rec.v2 = vz;
#pragma unroll
    for (int e = 0; e < 4; ++e) rec.v2[e] = f2bf(l[16 + e] * inv);
    bh8 d = vz;
    if (!bside) {
        d[0] = f2bf(-2.0f * px); d[1] = f2bf(-2.0f * py); d[2] = f2bf(-2.0f * pz);
        d[3] = f2bf(sqp);        d[4] = f2bf(1.0f);
    } else {
        d[0] = f2bf(px); d[1] = f2bf(py); d[2] = f2bf(pz);
        d[3] = f2bf(1.0f); d[4] = f2bf(sqp);
    }
    rec.d = d;
    return rec;
}

// Super-tile st -> (R,C): row R covers C in [R/2, gx); row R has gx - R/2
// tiles; prefix P(R) = gx*R - floor((R-1)^2/4), P(0)=0.  nst = 1056.
__global__ void __launch_bounds__(256, 4)
fcl_fused(const float* __restrict__ pc, const float* __restrict__ logits,
          float* __restrict__ psums, int* __restrict__ pcnts,
          unsigned* __restrict__ ticket, float* __restrict__ out,
          int NG, int nst) {
    const int tid = threadIdx.x;
    const int lane = tid & 63;
    const int w = tid >> 6;
    const int gx = NG >> 3, Rn = NG >> 2;
    const int st = blockIdx.x;

    // map st -> (R, C) via binary search on P(R)
    int lo = 0, hi = Rn - 1;
    while (lo < hi) {
        int mid = (lo + hi + 1) >> 1;
        int p = gx * mid - ((mid - 1) * (mid - 1)) / 4;
        if (p <= st) lo = mid; else hi = mid - 1;
    }
    const int R = lo;
    const int P = (R > 0) ? (gx * R - ((R - 1) * (R - 1)) / 4) : 0;
    const int C = (R >> 1) + (st - P);

    __shared__ bh8 shAS[4 * 2 * 64];     // 8 KB
    __shared__ bh8 shAD[4 * 64];         // 4 KB
    __shared__ bh8 shBS[8 * 2 * 64];     // 16 KB
    __shared__ bh8 shBD[8 * 64];         // 8 KB
    const bh8 vz = {0, 0, 0, 0, 0, 0, 0, 0};

    // prep B region: 256 points at C*256
    {
        Rec rec = make_rec(pc, logits, C * 256 + tid, true);
        int g = tid >> 5, r = tid & 31;
        shBS[(g * 2 + 0) * 64 + r]      = rec.v0;
        shBS[(g * 2 + 0) * 64 + r + 32] = rec.v1;
        shBS[(g * 2 + 1) * 64 + r]      = rec.v2;
        shBS[(g * 2 + 1) * 64 + r + 32] = vz;
        shBD[g * 64 + r]                = rec.d;
        shBD[g * 64 + r + 32]           = vz;
    }
    // prep A region: 128 points at R*128
    if (tid < 128) {
        Rec rec = make_rec(pc, logits, R * 128 + tid, false);
        int g = tid >> 5, r = tid & 31;
        shAS[(g * 2 + 0) * 64 + r]      = rec.v0;
        shAS[(g * 2 + 0) * 64 + r + 32] = rec.v1;
        shAS[(g * 2 + 1) * 64 + r]      = rec.v2;
        shAS[(g * 2 + 1) * 64 + r + 32] = vz;
        shAD[g * 64 + r]                = rec.d;
        shAD[g * 64 + r + 32]           = vz;
    }
    __syncthreads();

    const int rg = R * 4 + w;             // this wave's global row-group
    const bh8 aS0 = shAS[(w * 2 + 0) * 64 + lane];
    const bh8 aS1 = shAS[(w * 2 + 1) * 64 + lane];
    const bh8 aD  = shAD[w * 64 + lane];

    float psD = 0.f, psO = 0.f;
    int   cnD = 0,   cnO = 0;

#pragma unroll
    for (int k = 0; k < 8; ++k) {
        const int cg = C * 8 + k;         // wave-uniform
        if (cg < rg) continue;            // below diagonal
        bh8 b0 = shBS[(k * 2 + 0) * 64 + lane];
        bh8 b1 = shBS[(k * 2 + 1) * 64 + lane];
        bh8 bd = shBD[k * 64 + lane];
        fx16 accS = {0.f};
        accS = __builtin_amdgcn_mfma_f32_32x32x16_bf16(aS0, b0, accS, 0, 0, 0);
        accS = __builtin_amdgcn_mfma_f32_32x32x16_bf16(aS1, b1, accS, 0, 0, 0);
        fx16 accD = {0.f};
        accD = __builtin_amdgcn_mfma_f32_32x32x16_bf16(aD, bd, accD, 0, 0, 0);
        if (cg == rg) {
#pragma unroll
            for (int r2 = 0; r2 < 16; ++r2) {
                bool cc = accD[r2] > 4.0f;
                psD += cc ? fmaxf(accS[r2], 0.f) : 0.f;
                cnD += cc ? 1 : 0;
            }
        } else {
#pragma unroll
            for (int r2 = 0; r2 < 16; ++r2) {
                bool cc = accD[r2] > 4.0f;
                psO += cc ? fmaxf(accS[r2], 0.f) : 0.f;
                cnO += cc ? 1 : 0;
            }
        }
    }

    // fold x2 off-diagonal weight; wave + block reduce into private slot
    float ps = psD + 2.0f * psO;
    int   cn = cnD + 2 * cnO;
#pragma unroll
    for (int off = 32; off > 0; off >>= 1) {
        ps += __shfl_down(ps, off);
        cn += __shfl_down(cn, off);
    }
    __shared__ float sps[4];
    __shared__ int   scs[4];
    if (lane == 0) { sps[w] = ps; scs[w] = cn; }
    __syncthreads();

    __shared__ unsigned sIsLast;
    if (tid == 0) {
        psums[st] = sps[0] + sps[1] + sps[2] + sps[3];
        pcnts[st] = scs[0] + scs[1] + scs[2] + scs[3];
        __threadfence();                           // release partials
        unsigned old = atomicAdd(ticket, 1u);      // ticket starts at 0 (memset)
        sIsLast = (old == (unsigned)(nst - 1)) ? 1u : 0u;
    }
    __syncthreads();

    if (sIsLast) {                                 // true last arriver
        __threadfence();                           // acquire all partials
        float s = 0.f;
        int c = 0;
        for (int k = tid; k < nst; k += 256) { s += psums[k]; c += pcnts[k]; }
#pragma unroll
        for (int off = 32; off > 0; off >>= 1) {
            s += __shfl_down(s, off);
            c += __shfl_down(c, off);
        }
        __shared__ float fps[4];
        __shared__ int   fcs[4];
        if (lane == 0) { fps[w] = s; fcs[w] = c; }
        __syncthreads();
        if (tid == 0) {
            float ts = fps[0] + fps[1] + fps[2] + fps[3];
            int   tc = fcs[0] + fcs[1] + fcs[2] + fcs[3];
            out[0] = (tc > 0) ? ts / (float)tc : 1.0f;
        }
    }
}

extern "C" void kernel_launch(void* const* d_in, const int* in_sizes, int n_in,
                              void* d_out, int out_size, void* d_ws, size_t ws_size,
                              hipStream_t stream) {
    const float* pc     = (const float*)d_in[0];  // [N,3]
    const float* logits = (const float*)d_in[1];  // [N,20]
    float* out = (float*)d_out;

    const int N  = in_sizes[0] / 3;               // 8192
    const int NG = N / 32;                        // 256 groups
    const int gx = NG / 8, Rn = NG / 4;           // 32, 64
    const int nst = gx * Rn - ((Rn - 1) * (Rn - 1)) / 4;   // 1056 tiles

    float*    psums  = (float*)d_ws;                        // [nst]
    int*      pcnts  = (int*)(psums + nst);                 // [nst]
    unsigned* ticket = (unsigned*)(pcnts + nst + 32);       // own cacheline

    hipMemsetAsync(ticket, 0, sizeof(unsigned), stream);    // known start state
    fcl_fused<<<nst, 256, 0, stream>>>(pc, logits, psums, pcnts, ticket, out,
                                       NG, nst);
}

// Round 20
// 20.344 us; speedup vs baseline: 4.4309x; 1.9972x over previous
//
#include <hip/hip_runtime.h>

// ForegroundConsistencyLoss - N=8192, C=20.
// loss = mean over pairs {both fg, d2>4} of relu(cos_sim(logits_i, logits_j)).
//
// v10 = v6 structure (the 18.86us verified best: two plain dispatches, zero
// atomics/fences/memsets) + v8's verified 1D triangle enumeration so only
// the 1056 ACTIVE 128x256 super-tiles get blocks (v6 launched 2048 with 992
// early-exits), and fcl_final reduces 1056 slots instead of 2048.
//
// Evidence ledger: v3 contended atomics=+44us; v7 grid.sync=+60us; v9
// 4B-memset node=+22us -> device-scope coherence machinery is banned; two
// clean dispatches are cheaper than any single-dispatch reduction trick.
// MFMA fragments (r8), fg-sentinel d2 (r8), triangle weights (r9-r16),
// st->(R,C) map (r16-r18): all verified absmax 0.0.

#define C_CLS 20

typedef __attribute__((ext_vector_type(8)))  short bh8;    // 8 bf16 (4 VGPRs)
typedef __attribute__((ext_vector_type(16))) float fx16;   // 16 f32 acc
typedef __attribute__((ext_vector_type(4)))  float f4;

static __device__ __forceinline__ short f2bf(float x) {
    unsigned u = __float_as_uint(x);
    unsigned r = (u + 0x7fffu + ((u >> 16) & 1u)) >> 16;
    return (short)r;
}

struct Rec { bh8 v0, v1, v2, d; };

// bside=false -> d = A'-row [-2x,-2y,-2z,sq',1]; bside=true -> d = B'-col
// [x,y,z,1,sq'].  sq' = fg ? |p|^2 : -1e30 (folds fg mask into d2>4 test).
static __device__ __forceinline__ Rec make_rec(const float* __restrict__ pc,
                                               const float* __restrict__ logits,
                                               int i, bool bside) {
    const f4* lg4 = (const f4*)(logits + (size_t)i * C_CLS);  // 80B stride
    float l[C_CLS];
#pragma unroll
    for (int q = 0; q < 5; ++q) {
        f4 v = lg4[q];
        l[q * 4 + 0] = v.x; l[q * 4 + 1] = v.y; l[q * 4 + 2] = v.z; l[q * 4 + 3] = v.w;
    }
    float m = l[1];
#pragma unroll
    for (int k = 2; k < C_CLS; ++k) m = fmaxf(m, l[k]);
    bool fg = m > l[0];                 // argmax != 0 (ties -> idx 0 -> bg)
    float ss = 0.f;
#pragma unroll
    for (int k = 0; k < C_CLS; ++k) ss = fmaf(l[k], l[k], ss);
    float inv = 1.0f / fmaxf(sqrtf(ss), 1e-8f);
    float px = pc[i * 3 + 0], py = pc[i * 3 + 1], pz = pc[i * 3 + 2];
    float sq = px * px + py * py + pz * pz;
    float sqp = fg ? sq : -1.0e30f;

    Rec rec;
    bh8 vz = {0, 0, 0, 0, 0, 0, 0, 0};
#pragma unroll
    for (int e = 0; e < 8; ++e) rec.v0[e] = f2bf(l[e] * inv);
#pragma unroll
    for (int e = 0; e < 8; ++e) rec.v1[e] = f2bf(l[8 + e] * inv);
    rec.v2 = vz;
#pragma unroll
    for (int e = 0; e < 4; ++e) rec.v2[e] = f2bf(l[16 + e] * inv);
    bh8 d = vz;
    if (!bside) {
        d[0] = f2bf(-2.0f * px); d[1] = f2bf(-2.0f * py); d[2] = f2bf(-2.0f * pz);
        d[3] = f2bf(sqp);        d[4] = f2bf(1.0f);
    } else {
        d[0] = f2bf(px); d[1] = f2bf(py); d[2] = f2bf(pz);
        d[3] = f2bf(1.0f); d[4] = f2bf(sqp);
    }
    rec.d = d;
    return rec;
}

// Super-tile st -> (R,C): row R covers C in [R/2, gx); row R has gx - R/2
// tiles; prefix P(R) = gx*R - floor((R-1)^2/4), P(0)=0.  nst = 1056.
__global__ void __launch_bounds__(256, 4)
fcl_fused(const float* __restrict__ pc, const float* __restrict__ logits,
          float* __restrict__ psums, int* __restrict__ pcnts, int NG) {
    const int tid = threadIdx.x;
    const int lane = tid & 63;
    const int w = tid >> 6;
    const int gx = NG >> 3, Rn = NG >> 2;
    const int st = blockIdx.x;

    // map st -> (R, C) via binary search on P(R)
    int lo = 0, hi = Rn - 1;
    while (lo < hi) {
        int mid = (lo + hi + 1) >> 1;
        int p = gx * mid - ((mid - 1) * (mid - 1)) / 4;
        if (p <= st) lo = mid; else hi = mid - 1;
    }
    const int R = lo;
    const int P = (R > 0) ? (gx * R - ((R - 1) * (R - 1)) / 4) : 0;
    const int C = (R >> 1) + (st - P);

    __shared__ bh8 shAS[4 * 2 * 64];     // 8 KB
    __shared__ bh8 shAD[4 * 64];         // 4 KB
    __shared__ bh8 shBS[8 * 2 * 64];     // 16 KB
    __shared__ bh8 shBD[8 * 64];         // 8 KB
    const bh8 vz = {0, 0, 0, 0, 0, 0, 0, 0};

    // prep B region: 256 points at C*256
    {
        Rec rec = make_rec(pc, logits, C * 256 + tid, true);
        int g = tid >> 5, r = tid & 31;
        shBS[(g * 2 + 0) * 64 + r]      = rec.v0;
        shBS[(g * 2 + 0) * 64 + r + 32] = rec.v1;
        shBS[(g * 2 + 1) * 64 + r]      = rec.v2;
        shBS[(g * 2 + 1) * 64 + r + 32] = vz;
        shBD[g * 64 + r]                = rec.d;
        shBD[g * 64 + r + 32]           = vz;
    }
    // prep A region: 128 points at R*128
    if (tid < 128) {
        Rec rec = make_rec(pc, logits, R * 128 + tid, false);
        int g = tid >> 5, r = tid & 31;
        shAS[(g * 2 + 0) * 64 + r]      = rec.v0;
        shAS[(g * 2 + 0) * 64 + r + 32] = rec.v1;
        shAS[(g * 2 + 1) * 64 + r]      = rec.v2;
        shAS[(g * 2 + 1) * 64 + r + 32] = vz;
        shAD[g * 64 + r]                = rec.d;
        shAD[g * 64 + r + 32]           = vz;
    }
    __syncthreads();

    const int rg = R * 4 + w;             // this wave's global row-group
    const bh8 aS0 = shAS[(w * 2 + 0) * 64 + lane];
    const bh8 aS1 = shAS[(w * 2 + 1) * 64 + lane];
    const bh8 aD  = shAD[w * 64 + lane];

    float psD = 0.f, psO = 0.f;
    int   cnD = 0,   cnO = 0;

#pragma unroll
    for (int k = 0; k < 8; ++k) {
        const int cg = C * 8 + k;         // wave-uniform
        if (cg < rg) continue;            // below diagonal
        bh8 b0 = shBS[(k * 2 + 0) * 64 + lane];
        bh8 b1 = shBS[(k * 2 + 1) * 64 + lane];
        bh8 bd = shBD[k * 64 + lane];
        fx16 accS = {0.f};
        accS = __builtin_amdgcn_mfma_f32_32x32x16_bf16(aS0, b0, accS, 0, 0, 0);
        accS = __builtin_amdgcn_mfma_f32_32x32x16_bf16(aS1, b1, accS, 0, 0, 0);
        fx16 accD = {0.f};
        accD = __builtin_amdgcn_mfma_f32_32x32x16_bf16(aD, bd, accD, 0, 0, 0);
        if (cg == rg) {
#pragma unroll
            for (int r2 = 0; r2 < 16; ++r2) {
                bool cc = accD[r2] > 4.0f;
                psD += cc ? fmaxf(accS[r2], 0.f) : 0.f;
                cnD += cc ? 1 : 0;
            }
        } else {
#pragma unroll
            for (int r2 = 0; r2 < 16; ++r2) {
                bool cc = accD[r2] > 4.0f;
                psO += cc ? fmaxf(accS[r2], 0.f) : 0.f;
                cnO += cc ? 1 : 0;
            }
        }
    }

    // fold x2 off-diagonal weight; wave + block reduce into private slot
    float ps = psD + 2.0f * psO;
    int   cn = cnD + 2 * cnO;
#pragma unroll
    for (int off = 32; off > 0; off >>= 1) {
        ps += __shfl_down(ps, off);
        cn += __shfl_down(cn, off);
    }
    __shared__ float sps[4];
    __shared__ int   scs[4];
    if (lane == 0) { sps[w] = ps; scs[w] = cn; }
    __syncthreads();
    if (tid == 0) {
        psums[st] = sps[0] + sps[1] + sps[2] + sps[3];
        pcnts[st] = scs[0] + scs[1] + scs[2] + scs[3];
    }
}

__global__ void __launch_bounds__(256) fcl_final(const float* __restrict__ psums,
                                                 const int* __restrict__ pcnts,
                                                 float* __restrict__ out, int nb) {
    float s = 0.f;
    int c = 0;
    for (int k = threadIdx.x; k < nb; k += 256) { s += psums[k]; c += pcnts[k]; }
#pragma unroll
    for (int off = 32; off > 0; off >>= 1) {
        s += __shfl_down(s, off);
        c += __shfl_down(c, off);
    }
    __shared__ float sps[4];
    __shared__ int   scs[4];
    int wid = threadIdx.x >> 6, lane = threadIdx.x & 63;
    if (lane == 0) { sps[wid] = s; scs[wid] = c; }
    __syncthreads();
    if (threadIdx.x == 0) {
        float ts = sps[0] + sps[1] + sps[2] + sps[3];
        int   tc = scs[0] + scs[1] + scs[2] + scs[3];
        out[0] = (tc > 0) ? ts / (float)tc : 1.0f;
    }
}

extern "C" void kernel_launch(void* const* d_in, const int* in_sizes, int n_in,
                              void* d_out, int out_size, void* d_ws, size_t ws_size,
                              hipStream_t stream) {
    const float* pc     = (const float*)d_in[0];  // [N,3]
    const float* logits = (const float*)d_in[1];  // [N,20]
    float* out = (float*)d_out;

    const int N  = in_sizes[0] / 3;               // 8192
    const int NG = N / 32;                        // 256 groups
    const int gx = NG / 8, Rn = NG / 4;           // 32, 64
    const int nst = gx * Rn - ((Rn - 1) * (Rn - 1)) / 4;   // 1056 tiles

    float* psums = (float*)d_ws;                  // [nst]
    int*   pcnts = (int*)(psums + nst);           // [nst]

    fcl_fused<<<nst, 256, 0, stream>>>(pc, logits, psums, pcnts, NG);
    fcl_final<<<1, 256, 0, stream>>>(psums, pcnts, out, nst);
}